// Round 1
// baseline (562.648 us; speedup 1.0000x reference)
//
#include <hip/hip_runtime.h>

#define B_ 8
#define C_ 512
#define L_ 16384
#define H_ 256
#define CL_ (C_*L_)
#define NB 64
#define LBLK (L_/NB)          // 256 l-blocks per batch
#define NKEEP 358             // int(512*0.7)
#define EPSV 1e-3f

typedef __attribute__((ext_vector_type(8))) short short8;   // 8 x bf16
typedef __attribute__((ext_vector_type(4))) float f32x4;

__device__ __forceinline__ unsigned short f2bf(float f){
  unsigned u = __builtin_bit_cast(unsigned, f);
  u = u + 0x7fffu + ((u >> 16) & 1u);        // RNE, finite inputs only
  return (unsigned short)(u >> 16);
}

// ---------------- K0: zero accumulators + convert gate weights to bf16 ----
__global__ __launch_bounds__(256) void k0_init(const float* __restrict__ w1,
    const float* __restrict__ w2, unsigned short* __restrict__ w1b,
    unsigned short* __restrict__ w2b, float* __restrict__ zreg){
  int i = blockIdx.x * 256 + threadIdx.x;
  if (i < H_*C_){ w1b[i] = f2bf(w1[i]); w2b[i] = f2bf(w2[i]); }
  if (i < 2*B_*C_) zreg[i] = 0.f;            // gsum + csum
}

// ---------------- K1: per-(b,c) sum & sumsq of x --------------------------
__global__ __launch_bounds__(256) void k1_stats(const float* __restrict__ x,
    float* __restrict__ sum_x, float* __restrict__ sumsq_x){
  int bc = blockIdx.x;
  const float4* xp = (const float4*)(x + (size_t)bc * L_);
  int t = threadIdx.x;
  float s = 0.f, q = 0.f;
  #pragma unroll
  for (int i=0;i<16;i++){
    float4 v = xp[t + 256*i];
    s += v.x + v.y + v.z + v.w;
    q += v.x*v.x + v.y*v.y + v.z*v.z + v.w*v.w;
  }
  #pragma unroll
  for (int m=1;m<64;m<<=1){ s += __shfl_xor(s, m); q += __shfl_xor(q, m); }
  __shared__ float ss[4], qq[4];
  if ((t & 63) == 0){ ss[t>>6] = s; qq[t>>6] = q; }
  __syncthreads();
  if (t == 0){
    sum_x[bc]   = ss[0]+ss[1]+ss[2]+ss[3];
    sumsq_x[bc] = qq[0]+qq[1]+qq[2]+qq[3];
  }
}

// ---------------- K2: gate MLP (bf16 MFMA) + csum -------------------------
// per block: 64 columns of one batch. LDS: cB[n][k=512] bf16 swizzled (64KB),
// reused for hB[n][k=256] after GEMM1.
__global__ __launch_bounds__(256,2) void k2_gate(const float* __restrict__ cg,
    const unsigned short* __restrict__ w1b, const unsigned short* __restrict__ w2b,
    const float* __restrict__ gb1, const float* __restrict__ gb2,
    float* __restrict__ gsum, float* __restrict__ csum)
{
  __shared__ alignas(16) char lds[65536];
  const int bid = blockIdx.x;
  const int b   = bid / LBLK;
  const int l0  = (bid % LBLK) * NB;
  const int t    = threadIdx.x;
  const int lane = t & 63;
  const int w    = t >> 6;
  const int ln15 = lane & 15;
  const int lhi  = lane >> 4;

  // ---- stage c block -> LDS bf16 [n][k] swizzled; fuse csum ----
  {
    const int l4 = t & 15;          // float4 index along l
    const int rp = t >> 4;          // row-pair group
    const float* cb = cg + (size_t)b * CL_ + l0;
    #pragma unroll
    for (int i=0;i<16;i++){
      int ch = 2*rp + 32*i;
      float4 fa = *(const float4*)(cb + (size_t)ch    *L_ + 4*l4);
      float4 fb = *(const float4*)(cb + (size_t)(ch+1)*L_ + 4*l4);
      float va[4] = {fa.x, fa.y, fa.z, fa.w};
      float vb[4] = {fb.x, fb.y, fb.z, fb.w};
      #pragma unroll
      for (int u=0;u<4;u++){
        int n = 4*l4 + u;
        unsigned p = (unsigned)f2bf(va[u]) | ((unsigned)f2bf(vb[u]) << 16);
        int off = (n*1024 + ch*2) ^ ((n & 7) << 4);
        *(unsigned*)(lds + off) = p;
      }
      float ra = fa.x+fa.y+fa.z+fa.w;
      float rb = fb.x+fb.y+fb.z+fb.w;
      ra += __shfl_xor(ra,1); ra += __shfl_xor(ra,2); ra += __shfl_xor(ra,4); ra += __shfl_xor(ra,8);
      rb += __shfl_xor(rb,1); rb += __shfl_xor(rb,2); rb += __shfl_xor(rb,4); rb += __shfl_xor(rb,8);
      if (ln15 == 0){
        atomicAdd(&csum[b*C_ + ch],     ra);
        atomicAdd(&csum[b*C_ + ch + 1], rb);
      }
    }
  }
  __syncthreads();

  f32x4 zero4 = {0.f,0.f,0.f,0.f};

  // ---- GEMM1: h[256][64] = W1(256x512) @ cB ; wave w owns rows [w*64, w*64+64)
  f32x4 acc1[4][4];
  #pragma unroll
  for (int mt=0;mt<4;mt++){
    #pragma unroll
    for (int nt=0;nt<4;nt++) acc1[mt][nt] = zero4;
  }
  const short8* A1 = (const short8*)w1b;
  for (int ks=0; ks<16; ks++){
    short8 af[4], bfr[4];
    #pragma unroll
    for (int mt=0;mt<4;mt++)
      af[mt] = A1[(w*64 + mt*16 + ln15)*64 + ks*4 + lhi];
    #pragma unroll
    for (int nt=0;nt<4;nt++){
      int n = nt*16 + ln15;
      int off = (n*1024 + (ks*32 + lhi*8)*2) ^ ((n & 7) << 4);
      bfr[nt] = *(const short8*)(lds + off);
    }
    #pragma unroll
    for (int mt=0;mt<4;mt++){
      #pragma unroll
      for (int nt=0;nt<4;nt++)
        acc1[mt][nt] = __builtin_amdgcn_mfma_f32_16x16x32_bf16(af[mt], bfr[nt], acc1[mt][nt], 0,0,0);
    }
  }
  __syncthreads();   // all cB reads done; LDS now reused for hB

  // ---- relu(+bias) -> hB[n][k=256] bf16 swizzled ----
  #pragma unroll
  for (int mt=0;mt<4;mt++){
    int m0 = w*64 + mt*16 + lhi*4;
    float b0 = gb1[m0], b1v = gb1[m0+1], b2v = gb1[m0+2], b3v = gb1[m0+3];
    #pragma unroll
    for (int nt=0;nt<4;nt++){
      int n = nt*16 + ln15;
      float r0 = fmaxf(acc1[mt][nt][0] + b0 , 0.f);
      float r1 = fmaxf(acc1[mt][nt][1] + b1v, 0.f);
      float r2 = fmaxf(acc1[mt][nt][2] + b2v, 0.f);
      float r3 = fmaxf(acc1[mt][nt][3] + b3v, 0.f);
      unsigned p01 = (unsigned)f2bf(r0) | ((unsigned)f2bf(r1)<<16);
      unsigned p23 = (unsigned)f2bf(r2) | ((unsigned)f2bf(r3)<<16);
      *(unsigned*)(lds + ((n*512 +  m0   *2) ^ ((n&7)<<4))) = p01;
      *(unsigned*)(lds + ((n*512 + (m0+2)*2) ^ ((n&7)<<4))) = p23;
    }
  }
  __syncthreads();

  // ---- GEMM2: out2[512][64] = W2(512x256) @ hB ; wave w owns rows [w*128, +128)
  f32x4 acc2[8][4];
  #pragma unroll
  for (int mt=0;mt<8;mt++){
    #pragma unroll
    for (int nt=0;nt<4;nt++) acc2[mt][nt] = zero4;
  }
  const short8* A2 = (const short8*)w2b;
  for (int ks=0; ks<8; ks++){
    short8 af[8], bfr[4];
    #pragma unroll
    for (int mt=0;mt<8;mt++)
      af[mt] = A2[(w*128 + mt*16 + ln15)*32 + ks*4 + lhi];
    #pragma unroll
    for (int nt=0;nt<4;nt++){
      int n = nt*16 + ln15;
      int off = (n*512 + (ks*32 + lhi*8)*2) ^ ((n & 7) << 4);
      bfr[nt] = *(const short8*)(lds + off);
    }
    #pragma unroll
    for (int mt=0;mt<8;mt++){
      #pragma unroll
      for (int nt=0;nt<4;nt++)
        acc2[mt][nt] = __builtin_amdgcn_mfma_f32_16x16x32_bf16(af[mt], bfr[nt], acc2[mt][nt], 0,0,0);
    }
  }

  // ---- sigmoid(+bias), sum over columns, atomic accumulate ----
  #pragma unroll
  for (int mt=0;mt<8;mt++){
    int r0 = w*128 + mt*16 + lhi*4;
    #pragma unroll
    for (int j=0;j<4;j++){
      float bias = gb2[r0 + j];
      float s = 0.f;
      #pragma unroll
      for (int nt=0;nt<4;nt++){
        float z = acc2[mt][nt][j] + bias;
        s += 1.f / (1.f + __expf(-z));
      }
      s += __shfl_xor(s,1); s += __shfl_xor(s,2); s += __shfl_xor(s,4); s += __shfl_xor(s,8);
      if (ln15 == 0) atomicAdd(&gsum[b*C_ + r0 + j], s);
    }
  }
}

// ---------------- K3: combine stats + tiny MLP -> per-(b,c) affine --------
__global__ __launch_bounds__(256) void k3_combine(const float* __restrict__ sum_x,
    const float* __restrict__ sumsq_x, const float* __restrict__ gsum,
    const float* __restrict__ csum,
    const float* __restrict__ w1m, const float* __restrict__ b1m,
    const float* __restrict__ w2m, const float* __restrict__ b2m,
    float* __restrict__ sA, float* __restrict__ sB)
{
  int b = blockIdx.x, t = threadIdx.x;
  __shared__ float sh_mu[512], sh_sg[512], sh_gm[512], sh_cond[512];
  __shared__ float sh_h2[256], sh_gam[512], sh_bet[512];
  __shared__ float redS[4], redQ[4], s_mul[2];
  float ps = 0.f, pq = 0.f;
  for (int c0=t; c0<512; c0+=256){
    float S = sum_x[b*512+c0], Q = sumsq_x[b*512+c0];
    float mu = S * (1.f/L_);
    float var = Q * (1.f/L_) - mu*mu;
    sh_mu[c0] = mu;
    sh_sg[c0] = sqrtf(var + EPSV);
    sh_gm[c0] = gsum[b*512+c0] * (1.f/L_);
    sh_cond[c0] = csum[b*512+c0] * (1.f/L_);
    ps += S; pq += Q;
  }
  #pragma unroll
  for (int m=1;m<64;m<<=1){ ps += __shfl_xor(ps,m); pq += __shfl_xor(pq,m); }
  if ((t&63)==0){ redS[t>>6]=ps; redQ[t>>6]=pq; }
  __syncthreads();
  if (t==0){
    float TS = redS[0]+redS[1]+redS[2]+redS[3];
    float TQ = redQ[0]+redQ[1]+redQ[2]+redQ[3];
    float mu_l = TS / (float)CL_;
    float var_l = TQ / (float)CL_ - mu_l*mu_l;
    s_mul[0] = mu_l;
    s_mul[1] = sqrtf(var_l + EPSV);
  }
  __syncthreads();
  // MLP layer 1 (fp32): h2[t] over 512 cond
  float acc = b1m[t];
  #pragma unroll 8
  for (int c0=0;c0<512;c0++) acc += w1m[t*512+c0] * sh_cond[c0];
  sh_h2[t] = fmaxf(acc, 0.f);
  __syncthreads();
  // MLP layer 2: 1024 outputs
  for (int gi=t; gi<1024; gi+=256){
    float a2 = b2m[gi];
    #pragma unroll 8
    for (int h=0;h<256;h++) a2 += w2m[gi*256+h] * sh_h2[h];
    if (gi < 512) sh_gam[gi] = a2; else sh_bet[gi-512] = a2;
  }
  __syncthreads();
  for (int c0=t; c0<512; c0+=256){
    float gm = sh_gm[c0];
    float mu = gm*sh_mu[c0] + (1.f-gm)*s_mul[0];
    float sg = gm*sh_sg[c0] + (1.f-gm)*s_mul[1];
    float a  = (1.f + sh_gam[c0]) / sg;
    float bb = sh_bet[c0] - a*mu;
    sA[b*512+c0] = a;
    sB[b*512+c0] = bb;
  }
}

// ---------------- K4: y = a*x+b -> out (unmasked), accumulate |y| ---------
__global__ __launch_bounds__(256) void k4_y_imp(const float* __restrict__ x,
    const float* __restrict__ sA, const float* __restrict__ sB,
    float* __restrict__ out, float* __restrict__ impsum){
  int bc = blockIdx.x;
  float a = sA[bc], bb = sB[bc];
  const float4* xp = (const float4*)(x + (size_t)bc * L_);
  float4* op = (float4*)(out + (size_t)bc * L_);
  int t = threadIdx.x;
  float s = 0.f;
  #pragma unroll
  for (int i=0;i<16;i++){
    float4 v = xp[t + 256*i];
    float4 y;
    y.x = fmaf(a, v.x, bb);
    y.y = fmaf(a, v.y, bb);
    y.z = fmaf(a, v.z, bb);
    y.w = fmaf(a, v.w, bb);
    s += fabsf(y.x)+fabsf(y.y)+fabsf(y.z)+fabsf(y.w);
    op[t + 256*i] = y;
  }
  #pragma unroll
  for (int m=1;m<64;m<<=1) s += __shfl_xor(s,m);
  __shared__ float ss[4];
  if ((t&63)==0) ss[t>>6] = s;
  __syncthreads();
  if (t==0) impsum[bc] = ss[0]+ss[1]+ss[2]+ss[3];
}

// ---------------- K5: per-b top-k mask (jax tie semantics) ----------------
__global__ __launch_bounds__(512) void k5_topk(const float* __restrict__ impsum,
                                               float* __restrict__ maskf){
  int b = blockIdx.x, c0 = threadIdx.x;
  __shared__ float v[512];
  v[c0] = impsum[b*512 + c0];
  __syncthreads();
  float me = v[c0];
  int cnt = 0;
  #pragma unroll 8
  for (int j=0;j<512;j++){
    float o = v[j];
    cnt += (o > me) || (o == me && j < c0);
  }
  maskf[b*512 + c0] = (cnt < NKEEP) ? 1.f : 0.f;
}

// ---------------- K6: zero masked-out channels in place -------------------
__global__ __launch_bounds__(256) void k6_zero(float* __restrict__ out,
                                               const float* __restrict__ maskf){
  int bc = blockIdx.x;
  if (maskf[bc] != 0.f) return;
  float4* op = (float4*)(out + (size_t)bc * L_);
  float4 z = {0.f,0.f,0.f,0.f};
  int t = threadIdx.x;
  #pragma unroll
  for (int i=0;i<16;i++) op[t + 256*i] = z;
}

extern "C" void kernel_launch(void* const* d_in, const int* in_sizes, int n_in,
                              void* d_out, int out_size, void* d_ws, size_t ws_size,
                              hipStream_t stream) {
  const float* x   = (const float*)d_in[0];
  const float* c   = (const float*)d_in[1];
  const float* gw1 = (const float*)d_in[2];
  const float* gb1 = (const float*)d_in[3];
  const float* gw2 = (const float*)d_in[4];
  const float* gb2 = (const float*)d_in[5];
  const float* mw1 = (const float*)d_in[6];
  const float* mb1 = (const float*)d_in[7];
  const float* mw2 = (const float*)d_in[8];
  const float* mb2 = (const float*)d_in[9];
  float* out = (float*)d_out;

  float* F       = (float*)d_ws;
  float* sum_x   = F;              // 4096
  float* sumsq_x = F + 4096;
  float* gsum    = F + 8192;
  float* csum    = F + 12288;
  float* sA      = F + 16384;
  float* sB      = F + 20480;
  float* impsum  = F + 24576;
  float* maskf   = F + 28672;
  unsigned short* w1b = (unsigned short*)((char*)d_ws + 131072);   // 256KB
  unsigned short* w2b = (unsigned short*)((char*)d_ws + 393216);   // 256KB
  // total ws use: 655360 bytes

  k0_init  <<<512,  256, 0, stream>>>(gw1, gw2, w1b, w2b, gsum);
  k1_stats <<<B_*C_,256, 0, stream>>>(x, sum_x, sumsq_x);
  k2_gate  <<<B_*LBLK, 256, 0, stream>>>(c, w1b, w2b, gb1, gb2, gsum, csum);
  k3_combine<<<B_,  256, 0, stream>>>(sum_x, sumsq_x, gsum, csum,
                                      mw1, mb1, mw2, mb2, sA, sB);
  k4_y_imp <<<B_*C_,256, 0, stream>>>(x, sA, sB, out, impsum);
  k5_topk  <<<B_,   512, 0, stream>>>(impsum, maskf);
  k6_zero  <<<B_*C_,256, 0, stream>>>(out, maskf);
}